// Round 16
// baseline (1794.168 us; speedup 1.0000x reference)
//
#include <hip/hip_runtime.h>
#include <hip/hip_bf16.h>
#include <math.h>

#define DIM 512
#define SEQ 2048
#define NB 2
#define NEG_INF (-1e30f)

typedef __bf16 bf16x8 __attribute__((ext_vector_type(8)));
typedef float f32x4 __attribute__((ext_vector_type(4)));

static __device__ __forceinline__ float wave_sum(float x) {
#pragma unroll
  for (int off = 32; off; off >>= 1) x += __shfl_xor(x, off, 64);
  return x;
}

static __device__ __forceinline__ bf16x8 pack8(float4 a, float4 b) {
  bf16x8 r;
  r[0] = (__bf16)a.x; r[1] = (__bf16)a.y; r[2] = (__bf16)a.z; r[3] = (__bf16)a.w;
  r[4] = (__bf16)b.x; r[5] = (__bf16)b.y; r[6] = (__bf16)b.z; r[7] = (__bf16)b.w;
  return r;
}

static __device__ __forceinline__ float4 mul4(float4 a, float4 b) {
  return make_float4(a.x * b.x, a.y * b.y, a.z * b.z, a.w * b.w);
}

static __device__ __forceinline__ void gload16(const void* g, void* l) {
  __builtin_amdgcn_global_load_lds((const __attribute__((address_space(1))) void*)g,
                                   (__attribute__((address_space(3))) void*)l, 16, 0, 0);
}

// top-4 select on one score row (scan loop form identical to topk_body's)
static __device__ __forceinline__ void topk_sel(const float* __restrict__ sc, int N, int lane,
                                                float rv[4], int ri[4]) {
  float v0 = NEG_INF, v1 = NEG_INF, v2 = NEG_INF, v3 = NEG_INF;
  int i0 = 0x7fffffff, i1 = 0x7fffffff, i2 = 0x7fffffff, i3 = 0x7fffffff;
  for (int s = lane; s < N; s += 64) {
    float x = sc[s];
    if (x > v3) {
      if (x > v0) { v3 = v2; i3 = i2; v2 = v1; i2 = i1; v1 = v0; i1 = i0; v0 = x; i0 = s; }
      else if (x > v1) { v3 = v2; i3 = i2; v2 = v1; i2 = i1; v1 = x; i1 = s; }
      else if (x > v2) { v3 = v2; i3 = i2; v2 = x; i2 = s; }
      else { v3 = x; i3 = s; }
    }
  }
  int ptr = 0;
#pragma unroll
  for (int r = 0; r < 4; ++r) {
    float cv = (ptr == 0) ? v0 : (ptr == 1) ? v1 : (ptr == 2) ? v2 : (ptr == 3) ? v3 : NEG_INF;
    int ci = (ptr == 0) ? i0 : (ptr == 1) ? i1 : (ptr == 2) ? i2 : (ptr == 3) ? i3 : 0x7fffffff;
    float bv = cv;
    int bi = ci;
#pragma unroll
    for (int off = 32; off; off >>= 1) {
      float ov = __shfl_xor(bv, off, 64);
      int oi = __shfl_xor(bi, off, 64);
      if (ov > bv || (ov == bv && oi < bi)) { bv = ov; bi = oi; }
    }
    rv[r] = bv;
    ri[r] = bi;
    if (bi == ci) ptr++;
  }
}

// ---------------- embed gather ----------------
__global__ __launch_bounds__(128) void k_embed(const int* __restrict__ tok,
                                               const float* __restrict__ emb,
                                               float* __restrict__ sS,
                                               float* __restrict__ sV) {
  long row = blockIdx.x;
  int t = tok[row];
  const float4* src = (const float4*)(emb + (long)t * DIM);
  float4* a = (float4*)(sS + row * DIM);
  float4* b = (float4*)(sV + row * DIM);
  int i = threadIdx.x;
  float4 v = src[i];
  a[i] = v;
  b[i] = v;
}

// ---- broadcast pe -> f32 state/val + bf16 mirror + fused first-layer A-panel ----
__global__ __launch_bounds__(256) void k_bcast2(const float* __restrict__ pe,
                                                float* __restrict__ s, float* __restrict__ v,
                                                __bf16* __restrict__ mb,
                                                const float* __restrict__ wA,
                                                __bf16* __restrict__ awbOut,
                                                int N, int Npad) {
  int wid = threadIdx.x >> 6, lane = threadIdx.x & 63;
  long row = (long)blockIdx.x * 4 + wid;
  if (row >= (long)NB * Npad) return;
  int b = (int)(row / Npad), m = (int)(row % Npad);
  int d0 = lane * 8;
  if (m < N) {
    float4 x0 = *(const float4*)(pe + (long)m * DIM + d0);
    float4 x1 = *(const float4*)(pe + (long)m * DIM + d0 + 4);
    long fo = ((long)b * N + m) * DIM + d0;
    *(float4*)(s + fo) = x0; *(float4*)(s + fo + 4) = x1;
    *(float4*)(v + fo) = x0; *(float4*)(v + fo + 4) = x1;
    *(bf16x8*)(mb + row * DIM + d0) = pack8(x0, x1);
    float4 w0 = *(const float4*)(wA + d0);
    float4 w1 = *(const float4*)(wA + d0 + 4);
    *(bf16x8*)(awbOut + row * DIM + d0) = pack8(mul4(x0, w0), mul4(x1, w1));
  } else {
    bf16x8 z;
#pragma unroll
    for (int i = 0; i < 8; ++i) z[i] = (__bf16)0.f;
    *(bf16x8*)(mb + row * DIM + d0) = z;
    *(bf16x8*)(awbOut + row * DIM + d0) = z;
  }
}

// ---------------- readout_w transpose+cvt ----------------
__global__ __launch_bounds__(256) void k_transpose_rw(const float* __restrict__ in,
                                                      __bf16* __restrict__ out) {
  __shared__ float t[32][33];
  int tx = threadIdx.x, ty = threadIdx.y;
  int n0 = blockIdx.x * 32, k0 = blockIdx.y * 32;
#pragma unroll
  for (int i = 0; i < 4; ++i)
    t[ty + i * 8][tx] = in[(long)(k0 + ty + i * 8) * 32000 + n0 + tx];
  __syncthreads();
#pragma unroll
  for (int i = 0; i < 4; ++i)
    out[(long)(n0 + ty + i * 8) * DIM + k0 + tx] = (__bf16)t[tx][ty + i * 8];
}

// ---- causal window-4 propagation; emits bf16 mirrors: s, s*wE, s*wC ----
__global__ __launch_bounds__(256) void k_window(const float* __restrict__ sS,
                                                const float* __restrict__ sV,
                                                const float* __restrict__ w,
                                                float* __restrict__ oS,
                                                float* __restrict__ oV,
                                                __bf16* __restrict__ oSb,
                                                const float* __restrict__ wE,
                                                const float* __restrict__ wC,
                                                __bf16* __restrict__ awbE,
                                                __bf16* __restrict__ awbC) {
  int wid = threadIdx.x >> 6, lane = threadIdx.x & 63;
  long row = (long)blockIdx.x * 4 + wid;
  int i = (int)(row & (SEQ - 1));
  int d0 = lane * 8;
  const float* ps = sS + row * DIM + d0;
  const float* pv = sV + row * DIM + d0;
  float4 s0 = *(const float4*)ps;
  float4 s1 = *(const float4*)(ps + 4);
  float4 w0 = *(const float4*)(w + d0);
  float4 w1 = *(const float4*)(w + d0 + 4);
  float4 aw0 = mul4(s0, w0);
  float4 aw1 = mul4(s1, w1);
  float4 nS0[4], nS1[4], nV0[4], nV1[4];
  float sc[4];
#pragma unroll
  for (int k = 0; k < 4; ++k) {
    bool valid = (i >= k + 1);
    const float* qs = ps - (long)(k + 1) * DIM;
    const float* qv = pv - (long)(k + 1) * DIM;
    if (valid) {
      nS0[k] = *(const float4*)qs;
      nS1[k] = *(const float4*)(qs + 4);
      nV0[k] = *(const float4*)qv;
      nV1[k] = *(const float4*)(qv + 4);
    } else {
      nS0[k] = make_float4(0.f, 0.f, 0.f, 0.f);
      nS1[k] = nS0[k]; nV0[k] = nS0[k]; nV1[k] = nS0[k];
    }
    sc[k] = aw0.x * nS0[k].x + aw0.y * nS0[k].y + aw0.z * nS0[k].z + aw0.w * nS0[k].w +
            aw1.x * nS1[k].x + aw1.y * nS1[k].y + aw1.z * nS1[k].z + aw1.w * nS1[k].w;
  }
#pragma unroll
  for (int k = 0; k < 4; ++k) sc[k] = wave_sum(sc[k]);
  float m = NEG_INF;
#pragma unroll
  for (int k = 0; k < 4; ++k)
    if (i >= k + 1 && sc[k] > m) m = sc[k];
  float p[4];
  float Z = 0.f;
#pragma unroll
  for (int k = 0; k < 4; ++k) {
    p[k] = (i >= k + 1) ? expf(sc[k] - m) : 0.f;
    Z += p[k];
  }
  float invZ = (Z > 0.f) ? (1.f / Z) : 0.f;
  float4 v0 = *(const float4*)pv;
  float4 v1 = *(const float4*)(pv + 4);
  float4 os0 = s0, os1 = s1, ov0 = v0, ov1 = v1;
#pragma unroll
  for (int k = 0; k < 4; ++k) {
    float c = 0.25f * p[k] * invZ;
    os0.x += c * nS0[k].x; os0.y += c * nS0[k].y; os0.z += c * nS0[k].z; os0.w += c * nS0[k].w;
    os1.x += c * nS1[k].x; os1.y += c * nS1[k].y; os1.z += c * nS1[k].z; os1.w += c * nS1[k].w;
    ov0.x += c * nV0[k].x; ov0.y += c * nV0[k].y; ov0.z += c * nV0[k].z; ov0.w += c * nV0[k].w;
    ov1.x += c * nV1[k].x; ov1.y += c * nV1[k].y; ov1.z += c * nV1[k].z; ov1.w += c * nV1[k].w;
  }
  *(float4*)(oS + row * DIM + d0) = os0;
  *(float4*)(oS + row * DIM + d0 + 4) = os1;
  *(float4*)(oV + row * DIM + d0) = ov0;
  *(float4*)(oV + row * DIM + d0 + 4) = ov1;
  *(bf16x8*)(oSb + row * DIM + d0) = pack8(os0, os1);
  float4 we0 = *(const float4*)(wE + d0);
  float4 we1 = *(const float4*)(wE + d0 + 4);
  *(bf16x8*)(awbE + row * DIM + d0) = pack8(mul4(os0, we0), mul4(os1, we1));
  float4 wc0 = *(const float4*)(wC + d0);
  float4 wc1 = *(const float4*)(wC + d0 + 4);
  *(bf16x8*)(awbC + row * DIM + d0) = pack8(mul4(os0, wc0), mul4(os1, wc1));
}

// ------ grouped score GEMM: two sub-GEMMs per dispatch, 3-deep ring + counted vmcnt ------
__global__ __launch_bounds__(256) void k_mfma_g2(
    const __bf16* __restrict__ A1, const __bf16* __restrict__ B1, float* __restrict__ C1,
    int Mpad1, int Npad1, int ldc1,
    const __bf16* __restrict__ A2, const __bf16* __restrict__ B2, float* __restrict__ C2,
    int Mpad2, int Npad2, int ldc2) {
  const __bf16* A; const __bf16* Bm; float* C;
  int Mpad, Npad, ldc;
  long my;
  int M1b = Mpad1 >> 7;
  if ((int)blockIdx.y < M1b) {
    A = A1; Bm = B1; C = C1; Mpad = Mpad1; Npad = Npad1; ldc = ldc1; my = blockIdx.y;
  } else {
    A = A2; Bm = B2; C = C2; Mpad = Mpad2; Npad = Npad2; ldc = ldc2; my = blockIdx.y - M1b;
  }
  const long n0 = (long)blockIdx.x * 128;
  if (n0 >= Npad) return;
  const long m0 = my * 128;

  __shared__ __align__(1024) char lds[49152];
  const int tid = threadIdx.x;
  const int wid = tid >> 6, lane = tid & 63;
  const int b = blockIdx.z;
  const char* Ab = (const char*)(A + ((long)b * Mpad + m0) * DIM);
  const char* Bb = (const char*)(Bm + ((long)b * Npad + n0) * DIM);
  const int mw = (wid >> 1) * 64, nw = (wid & 1) * 64;

  int srow[2], scol[2], dofs[2];
#pragma unroll
  for (int is = 0; is < 2; ++is) {
    int d = is * 4096 + wid * 1024 + lane * 16;
    int s = d ^ (((d >> 8) & 3) << 4);
    srow[is] = s >> 6;
    scol[is] = s & 63;
    dofs[is] = is * 4096 + wid * 1024;
  }
  int aoff[4], boff[4];
#pragma unroll
  for (int f = 0; f < 4; ++f) {
    int rowA = mw + f * 16 + (lane & 15);
    int byA = rowA * 64 + (lane >> 4) * 16;
    aoff[f] = byA ^ (((byA >> 8) & 3) << 4);
    int rowB = nw + f * 16 + (lane & 15);
    int byB = rowB * 64 + (lane >> 4) * 16;
    boff[f] = (byB ^ (((byB >> 8) & 3) << 4)) + 8192;
  }
  auto stage = [&](int buf, int k0) {
#pragma unroll
    for (int is = 0; is < 2; ++is) {
      gload16(Ab + (long)srow[is] * (DIM * 2) + k0 * 2 + scol[is], lds + buf * 16384 + dofs[is]);
      gload16(Bb + (long)srow[is] * (DIM * 2) + k0 * 2 + scol[is], lds + buf * 16384 + 8192 + dofs[is]);
    }
  };

  f32x4 acc[4][4] = {};
  stage(0, 0);
  stage(1, 32);
#pragma unroll
  for (int t = 0; t < 16; ++t) {
    if (t <= 13) {
      stage((t + 2) % 3, (t + 2) * 32);
      asm volatile("s_waitcnt vmcnt(8)" ::: "memory");
    } else if (t == 14) {
      asm volatile("s_waitcnt vmcnt(4)" ::: "memory");
    } else {
      asm volatile("s_waitcnt vmcnt(0)" ::: "memory");
    }
    __builtin_amdgcn_s_barrier();
    const char* base = lds + (t % 3) * 16384;
    bf16x8 af[4], bf[4];
#pragma unroll
    for (int f = 0; f < 4; ++f) {
      af[f] = *(const bf16x8*)(base + aoff[f]);
      bf[f] = *(const bf16x8*)(base + boff[f]);
    }
    asm volatile("s_waitcnt lgkmcnt(0)" ::: "memory");
    __builtin_amdgcn_sched_barrier(0);
    __builtin_amdgcn_s_barrier();
#pragma unroll
    for (int i = 0; i < 4; ++i)
#pragma unroll
      for (int j = 0; j < 4; ++j)
        acc[i][j] = __builtin_amdgcn_mfma_f32_16x16x32_bf16(af[i], bf[j], acc[i][j], 0, 0, 0);
  }
  float* Cb = C + ((long)b * Mpad + m0) * ldc + n0;
#pragma unroll
  for (int i = 0; i < 4; ++i) {
    int mrow = mw + i * 16 + (lane >> 4) * 4;
#pragma unroll
    for (int r = 0; r < 4; ++r) {
      long moff = (long)(mrow + r) * ldc;
#pragma unroll
      for (int j = 0; j < 4; ++j) {
        int ncol = nw + j * 16 + (lane & 15);
        Cb[moff + ncol] = acc[i][j][r];
      }
    }
  }
}

// -------- readout GEMM: 2-phase, XCD-chunked swizzle, NT stores --------
__global__ __launch_bounds__(256) void k_mfma_ro(const __bf16* __restrict__ A,
                                                 const __bf16* __restrict__ Bm,
                                                 float* __restrict__ C,
                                                 const float* __restrict__ bias,
                                                 int Mpad, int Npad, int ldc) {
  __shared__ __align__(1024) char lds[32768];
  const int tid = threadIdx.x;
  const int wid = tid >> 6, lane = tid & 63;
  long hw = (long)blockIdx.y * gridDim.x + blockIdx.x;
  long nwg = (long)gridDim.x * gridDim.y;
  long cpx = nwg >> 3;
  long l = (hw & 7) * cpx + (hw >> 3);
  const long m0 = (l % gridDim.x) * 128;
  const long n0 = (l / gridDim.x) * 128;
  const char* Ab = (const char*)(A + m0 * DIM);
  const char* Bb = (const char*)(Bm + n0 * DIM);
  const int mw = (wid >> 1) * 64, nw = (wid & 1) * 64;

  int srow[2], scol[2], dofs[2];
#pragma unroll
  for (int is = 0; is < 2; ++is) {
    int d = is * 4096 + wid * 1024 + lane * 16;
    int s = d ^ (((d >> 8) & 3) << 4);
    srow[is] = s >> 6;
    scol[is] = s & 63;
    dofs[is] = is * 4096 + wid * 1024;
  }
  int aoff[4], boff[4];
#pragma unroll
  for (int f = 0; f < 4; ++f) {
    int rowA = mw + f * 16 + (lane & 15);
    int byA = rowA * 64 + (lane >> 4) * 16;
    aoff[f] = byA ^ (((byA >> 8) & 3) << 4);
    int rowB = nw + f * 16 + (lane & 15);
    int byB = rowB * 64 + (lane >> 4) * 16;
    boff[f] = (byB ^ (((byB >> 8) & 3) << 4)) + 8192;
  }
  auto stage = [&](int buf, int k0) {
#pragma unroll
    for (int is = 0; is < 2; ++is) {
      gload16(Ab + (long)srow[is] * (DIM * 2) + k0 * 2 + scol[is], lds + buf * 16384 + dofs[is]);
      gload16(Bb + (long)srow[is] * (DIM * 2) + k0 * 2 + scol[is], lds + buf * 16384 + 8192 + dofs[is]);
    }
  };

  f32x4 acc[4][4] = {};
  stage(0, 0);
  asm volatile("s_waitcnt vmcnt(0)" ::: "memory");
  __syncthreads();
  int cur = 0;
  for (int k0 = 0; k0 < DIM; k0 += 32) {
    const bool more = (k0 + 32 < DIM);
    if (more) stage(cur ^ 1, k0 + 32);
    const char* base = lds + cur * 16384;
    bf16x8 af[4], bf[4];
#pragma unroll
    for (int f = 0; f < 4; ++f) {
      af[f] = *(const bf16x8*)(base + aoff[f]);
      bf[f] = *(const bf16x8*)(base + boff[f]);
    }
#pragma unroll
    for (int i = 0; i < 4; ++i)
#pragma unroll
      for (int j = 0; j < 4; ++j)
        acc[i][j] = __builtin_amdgcn_mfma_f32_16x16x32_bf16(af[i], bf[j], acc[i][j], 0, 0, 0);
    if (more) {
      asm volatile("s_waitcnt vmcnt(0)" ::: "memory");
      __syncthreads();
      cur ^= 1;
    }
  }
  float* Cb = C + m0 * ldc + n0;
  float bv[4];
#pragma unroll
  for (int j = 0; j < 4; ++j) bv[j] = bias[n0 + nw + j * 16 + (lane & 15)];
#pragma unroll
  for (int i = 0; i < 4; ++i) {
    int mrow = mw + i * 16 + (lane >> 4) * 4;
#pragma unroll
    for (int r = 0; r < 4; ++r) {
      long moff = (long)(mrow + r) * ldc;
#pragma unroll
      for (int j = 0; j < 4; ++j) {
        int ncol = nw + j * 16 + (lane & 15);
        __builtin_nontemporal_store(acc[i][j][r] + bv[j], &Cb[moff + ncol]);
      }
    }
  }
}

// ---- top-4 + softmax + gather + update body (unchanged; used by k_topk2) ----
static __device__ __forceinline__ void topk_body(
    long blk,
    const float* __restrict__ scores, int Mpad, int ldc,
    const float* __restrict__ srcS, const float* __restrict__ srcV,
    const float* __restrict__ baseS, const float* __restrict__ baseV,
    float* __restrict__ outS, float* __restrict__ outV,
    __bf16* __restrict__ outSb, int MpadMir,
    const float* __restrict__ wNext, __bf16* __restrict__ outAw,
    int M, int N, float scale) {
  int wid = threadIdx.x >> 6, lane = threadIdx.x & 63;
  long row = blk * 4 + wid;
  long total = (long)NB * M;
  if (row >= total) return;
  int b = (int)(row / M);
  int m = (int)(row - (long)b * M);
  float rv[4];
  int ri[4];
  topk_sel(scores + ((long)b * Mpad + m) * ldc, N, lane, rv, ri);
  float p0 = 1.f, p1 = expf(rv[1] - rv[0]), p2 = expf(rv[2] - rv[0]), p3 = expf(rv[3] - rv[0]);
  float invZ = 1.f / (p0 + p1 + p2 + p3);
  p0 *= invZ; p1 *= invZ; p2 *= invZ; p3 *= invZ;
  int d0 = lane * 8;
  long sb = (long)b * N;
  const float* gs0 = srcS + (sb + ri[0]) * DIM + d0;
  const float* gs1 = srcS + (sb + ri[1]) * DIM + d0;
  const float* gs2 = srcS + (sb + ri[2]) * DIM + d0;
  const float* gs3 = srcS + (sb + ri[3]) * DIM + d0;
  const float* gv0 = srcV + (sb + ri[0]) * DIM + d0;
  const float* gv1 = srcV + (sb + ri[1]) * DIM + d0;
  const float* gv2 = srcV + (sb + ri[2]) * DIM + d0;
  const float* gv3 = srcV + (sb + ri[3]) * DIM + d0;
  long ro = row * DIM + d0;
  float4 osv[2], qsv[2];
#pragma unroll
  for (int h = 0; h < 2; ++h) {
    float4 x0 = *(const float4*)(gs0 + h * 4);
    float4 x1 = *(const float4*)(gs1 + h * 4);
    float4 x2 = *(const float4*)(gs2 + h * 4);
    float4 x3 = *(const float4*)(gs3 + h * 4);
    float4 o = *(const float4*)(baseS + ro + h * 4);
    o.x += scale * (p0 * x0.x + p1 * x1.x + p2 * x2.x + p3 * x3.x);
    o.y += scale * (p0 * x0.y + p1 * x1.y + p2 * x2.y + p3 * x3.y);
    o.z += scale * (p0 * x0.z + p1 * x1.z + p2 * x2.z + p3 * x3.z);
    o.w += scale * (p0 * x0.w + p1 * x1.w + p2 * x2.w + p3 * x3.w);
    osv[h] = o;
    float4 y0 = *(const float4*)(gv0 + h * 4);
    float4 y1 = *(const float4*)(gv1 + h * 4);
    float4 y2 = *(const float4*)(gv2 + h * 4);
    float4 y3 = *(const float4*)(gv3 + h * 4);
    float4 q = *(const float4*)(baseV + ro + h * 4);
    q.x += scale * (p0 * y0.x + p1 * y1.x + p2 * y2.x + p3 * y3.x);
    q.y += scale * (p0 * y0.y + p1 * y1.y + p2 * y2.y + p3 * y3.y);
    q.z += scale * (p0 * y0.z + p1 * y1.z + p2 * y2.z + p3 * y3.z);
    q.w += scale * (p0 * y0.w + p1 * y1.w + p2 * y2.w + p3 * y3.w);
    qsv[h] = q;
  }
#pragma unroll
  for (int h = 0; h < 2; ++h) {
    *(float4*)(outS + ro + h * 4) = osv[h];
    *(float4*)(outV + ro + h * 4) = qsv[h];
  }
  if (outSb) {
    *(bf16x8*)(outSb + ((long)b * MpadMir + m) * DIM + d0) = pack8(osv[0], osv[1]);
  }
  if (outAw) {
    float4 w0 = *(const float4*)(wNext + d0);
    float4 w1 = *(const float4*)(wNext + d0 + 4);
    *(bf16x8*)(outAw + ((long)b * MpadMir + m) * DIM + d0) =
        pack8(mul4(osv[0], w0), mul4(osv[1], w1));
  }
}

// merged pair of INDEPENDENT top-k problems (e and c) in one dispatch
__global__ __launch_bounds__(256) void k_topk2(
    const float* __restrict__ sc1, int Mpad1, int ldc1,
    const float* __restrict__ srcS1, const float* __restrict__ srcV1,
    const float* __restrict__ baseS1, const float* __restrict__ baseV1,
    float* __restrict__ outS1, float* __restrict__ outV1,
    __bf16* __restrict__ outSb1, int MpadMir1,
    const float* __restrict__ wNext1, __bf16* __restrict__ outAw1,
    int M1, int N1, float scale1, int nblk1,
    const float* __restrict__ sc2, int Mpad2, int ldc2,
    const float* __restrict__ srcS2, const float* __restrict__ srcV2,
    const float* __restrict__ baseS2, const float* __restrict__ baseV2,
    float* __restrict__ outS2, float* __restrict__ outV2,
    __bf16* __restrict__ outSb2, int MpadMir2,
    const float* __restrict__ wNext2, __bf16* __restrict__ outAw2,
    int M2, int N2, float scale2) {
  if ((int)blockIdx.x < nblk1) {
    topk_body(blockIdx.x, sc1, Mpad1, ldc1, srcS1, srcV1, baseS1, baseV1, outS1, outV1,
              outSb1, MpadMir1, wNext1, outAw1, M1, N1, scale1);
  } else {
    topk_body((long)blockIdx.x - nblk1, sc2, Mpad2, ldc2, srcS2, srcV2, baseS2, baseV2,
              outS2, outV2, outSb2, MpadMir2, wNext2, outAw2, M2, N2, scale2);
  }
}

// ---- merged 6a+6b: both e->s and c->s top-k blends applied in order, + fused tanh/LN ----
// Per-element fp sequence identical to the former two-kernel path:
// o = base + scale*blendE; o += scale*blendC; then tanh/LN.
__global__ __launch_bounds__(256) void k_topk_ec(
    const float* __restrict__ sc1, int ldc1,
    const float* __restrict__ srcS1, const float* __restrict__ srcV1, int N1,
    const float* __restrict__ sc2, int ldc2,
    const float* __restrict__ srcS2, const float* __restrict__ srcV2, int N2,
    const float* __restrict__ baseS, const float* __restrict__ baseV,
    float* __restrict__ outS, float* __restrict__ outV,
    const float* __restrict__ lnG, const float* __restrict__ lnB,
    __bf16* __restrict__ outValb, float scale) {
  int wid = threadIdx.x >> 6, lane = threadIdx.x & 63;
  long row = (long)blockIdx.x * 4 + wid;  // covers NB*SEQ exactly
  int b = (int)(row >> 11);
  int m = (int)(row & (SEQ - 1));
  float rv1[4], rv2[4];
  int ri1[4], ri2[4];
  topk_sel(sc1 + ((long)b * SEQ + m) * ldc1, N1, lane, rv1, ri1);
  topk_sel(sc2 + ((long)b * SEQ + m) * ldc2, N2, lane, rv2, ri2);
  float pa0 = 1.f, pa1 = expf(rv1[1] - rv1[0]), pa2 = expf(rv1[2] - rv1[0]),
        pa3 = expf(rv1[3] - rv1[0]);
  float iZ1 = 1.f / (pa0 + pa1 + pa2 + pa3);
  pa0 *= iZ1; pa1 *= iZ1; pa2 *= iZ1; pa3 *= iZ1;
  float pb0 = 1.f, pb1 = expf(rv2[1] - rv2[0]), pb2 = expf(rv2[2] - rv2[0]),
        pb3 = expf(rv2[3] - rv2[0]);
  float iZ2 = 1.f / (pb0 + pb1 + pb2 + pb3);
  pb0 *= iZ2; pb1 *= iZ2; pb2 *= iZ2; pb3 *= iZ2;
  int d0 = lane * 8;
  long s1 = (long)b * N1, s2 = (long)b * N2;
  const float* es0 = srcS1 + (s1 + ri1[0]) * DIM + d0;
  const float* es1 = srcS1 + (s1 + ri1[1]) * DIM + d0;
  const float* es2 = srcS1 + (s1 + ri1[2]) * DIM + d0;
  const float* es3 = srcS1 + (s1 + ri1[3]) * DIM + d0;
  const float* ev0 = srcV1 + (s1 + ri1[0]) * DIM + d0;
  const float* ev1 = srcV1 + (s1 + ri1[1]) * DIM + d0;
  const float* ev2 = srcV1 + (s1 + ri1[2]) * DIM + d0;
  const float* ev3 = srcV1 + (s1 + ri1[3]) * DIM + d0;
  const float* fs0 = srcS2 + (s2 + ri2[0]) * DIM + d0;
  const float* fs1 = srcS2 + (s2 + ri2[1]) * DIM + d0;
  const float* fs2 = srcS2 + (s2 + ri2[2]) * DIM + d0;
  const float* fs3 = srcS2 + (s2 + ri2[3]) * DIM + d0;
  const float* fv0 = srcV2 + (s2 + ri2[0]) * DIM + d0;
  const float* fv1 = srcV2 + (s2 + ri2[1]) * DIM + d0;
  const float* fv2 = srcV2 + (s2 + ri2[2]) * DIM + d0;
  const float* fv3 = srcV2 + (s2 + ri2[3]) * DIM + d0;
  long ro = row * DIM + d0;
  float4 osv[2], qsv[2];
#pragma unroll
  for (int h = 0; h < 2; ++h) {
    // e blend (matches former 6a)
    float4 x0 = *(const float4*)(es0 + h * 4);
    float4 x1 = *(const float4*)(es1 + h * 4);
    float4 x2 = *(const float4*)(es2 + h * 4);
    float4 x3 = *(const float4*)(es3 + h * 4);
    float4 o = *(const float4*)(baseS + ro + h * 4);
    o.x += scale * (pa0 * x0.x + pa1 * x1.x + pa2 * x2.x + pa3 * x3.x);
    o.y += scale * (pa0 * x0.y + pa1 * x1.y + pa2 * x2.y + pa3 * x3.y);
    o.z += scale * (pa0 * x0.z + pa1 * x1.z + pa2 * x2.z + pa3 * x3.z);
    o.w += scale * (pa0 * x0.w + pa1 * x1.w + pa2 * x2.w + pa3 * x3.w);
    float4 y0 = *(const float4*)(ev0 + h * 4);
    float4 y1 = *(const float4*)(ev1 + h * 4);
    float4 y2 = *(const float4*)(ev2 + h * 4);
    float4 y3 = *(const float4*)(ev3 + h * 4);
    float4 q = *(const float4*)(baseV + ro + h * 4);
    q.x += scale * (pa0 * y0.x + pa1 * y1.x + pa2 * y2.x + pa3 * y3.x);
    q.y += scale * (pa0 * y0.y + pa1 * y1.y + pa2 * y2.y + pa3 * y3.y);
    q.z += scale * (pa0 * y0.z + pa1 * y1.z + pa2 * y2.z + pa3 * y3.z);
    q.w += scale * (pa0 * y0.w + pa1 * y1.w + pa2 * y2.w + pa3 * y3.w);
    // c blend (matches former 6b, applied on 6a's result)
    x0 = *(const float4*)(fs0 + h * 4);
    x1 = *(const float4*)(fs1 + h * 4);
    x2 = *(const float4*)(fs2 + h * 4);
    x3 = *(const float4*)(fs3 + h * 4);
    o.x += scale * (pb0 * x0.x + pb1 * x1.x + pb2 * x2.x + pb3 * x3.x);
    o.y += scale * (pb0 * x0.y + pb1 * x1.y + pb2 * x2.y + pb3 * x3.y);
    o.z += scale * (pb0 * x0.z + pb1 * x1.z + pb2 * x2.z + pb3 * x3.z);
    o.w += scale * (pb0 * x0.w + pb1 * x1.w + pb2 * x2.w + pb3 * x3.w);
    y0 = *(const float4*)(fv0 + h * 4);
    y1 = *(const float4*)(fv1 + h * 4);
    y2 = *(const float4*)(fv2 + h * 4);
    y3 = *(const float4*)(fv3 + h * 4);
    q.x += scale * (pb0 * y0.x + pb1 * y1.x + pb2 * y2.x + pb3 * y3.x);
    q.y += scale * (pb0 * y0.y + pb1 * y1.y + pb2 * y2.y + pb3 * y3.y);
    q.z += scale * (pb0 * y0.z + pb1 * y1.z + pb2 * y2.z + pb3 * y3.z);
    q.w += scale * (pb0 * y0.w + pb1 * y1.w + pb2 * y2.w + pb3 * y3.w);
    osv[h] = o;
    qsv[h] = q;
  }
  // fused s stabilize: tanh on state, layernorm on val (same op order as before)
  osv[0].x = tanhf(osv[0].x); osv[0].y = tanhf(osv[0].y);
  osv[0].z = tanhf(osv[0].z); osv[0].w = tanhf(osv[0].w);
  osv[1].x = tanhf(osv[1].x); osv[1].y = tanhf(osv[1].y);
  osv[1].z = tanhf(osv[1].z); osv[1].w = tanhf(osv[1].w);
  float sum = qsv[0].x + qsv[0].y + qsv[0].z + qsv[0].w +
              qsv[1].x + qsv[1].y + qsv[1].z + qsv[1].w;
  sum = wave_sum(sum);
  float mu = sum * (1.f / DIM);
  float d[8] = {qsv[0].x - mu, qsv[0].y - mu, qsv[0].z - mu, qsv[0].w - mu,
                qsv[1].x - mu, qsv[1].y - mu, qsv[1].z - mu, qsv[1].w - mu};
  float ss = d[0]*d[0] + d[1]*d[1] + d[2]*d[2] + d[3]*d[3] +
             d[4]*d[4] + d[5]*d[5] + d[6]*d[6] + d[7]*d[7];
  ss = wave_sum(ss);
  float rs = rsqrtf(ss * (1.f / DIM) + 1e-5f);
  float4 g0 = *(const float4*)(lnG + d0);
  float4 g1 = *(const float4*)(lnG + d0 + 4);
  float4 b0 = *(const float4*)(lnB + d0);
  float4 b1 = *(const float4*)(lnB + d0 + 4);
  qsv[0].x = d[0] * rs * g0.x + b0.x; qsv[0].y = d[1] * rs * g0.y + b0.y;
  qsv[0].z = d[2] * rs * g0.z + b0.z; qsv[0].w = d[3] * rs * g0.w + b0.w;
  qsv[1].x = d[4] * rs * g1.x + b1.x; qsv[1].y = d[5] * rs * g1.y + b1.y;
  qsv[1].z = d[6] * rs * g1.z + b1.z; qsv[1].w = d[7] * rs * g1.w + b1.w;
#pragma unroll
  for (int h = 0; h < 2; ++h) {
    *(float4*)(outS + ro + h * 4) = osv[h];
    *(float4*)(outV + ro + h * 4) = qsv[h];
  }
  if (outValb) {
    *(bf16x8*)(outValb + ro) = pack8(qsv[0], qsv[1]);
  }
}

// ---- stabilize (e/c, non-stage-final layers) + fused next-layer s->B A-panel emit ----
__global__ __launch_bounds__(256) void k_stab(float* __restrict__ state,
                                              float* __restrict__ val,
                                              const float* __restrict__ g,
                                              const float* __restrict__ beta,
                                              const float* __restrict__ wNext,
                                              __bf16* __restrict__ awbOut,
                                              int M, int Mpad) {
  int wid = threadIdx.x >> 6, lane = threadIdx.x & 63;
  long row = (long)blockIdx.x * 4 + wid;
  if (row >= (long)NB * M) return;
  int d0 = lane * 8;
  float* ps = state + row * DIM + d0;
  float4 s0 = *(float4*)ps;
  float4 s1 = *(float4*)(ps + 4);
  s0.x = tanhf(s0.x); s0.y = tanhf(s0.y); s0.z = tanhf(s0.z); s0.w = tanhf(s0.w);
  s1.x = tanhf(s1.x); s1.y = tanhf(s1.y); s1.z = tanhf(s1.z); s1.w = tanhf(s1.w);
  *(float4*)ps = s0;
  *(float4*)(ps + 4) = s1;
  float* pv = val + row * DIM + d0;
  float4 x0 = *(float4*)pv;
  float4 x1 = *(float4*)(pv + 4);
  float sum = x0.x + x0.y + x0.z + x0.w + x1.x + x1.y + x1.z + x1.w;
  sum = wave_sum(sum);
  float mu = sum * (1.f / DIM);
  float d[8] = {x0.x - mu, x0.y - mu, x0.z - mu, x0.w - mu,
                x1.x - mu, x1.y - mu, x1.z - mu, x1.w - mu};
  float ss = d[0]*d[0] + d[1]*d[1] + d[2]*d[2] + d[3]*d[3] + d[4]*d[4] + d[5]*d[5] + d[6]*d[6] + d[7]*d[7];
  ss = wave_sum(ss);
  float rs = rsqrtf(ss * (1.f / DIM) + 1e-5f);
  float4 g0 = *(const float4*)(g + d0);
  float4 g1 = *(const float4*)(g + d0 + 4);
  float4 b0 = *(const float4*)(beta + d0);
  float4 b1 = *(const float4*)(beta + d0 + 4);
  x0.x = d[0] * rs * g0.x + b0.x; x0.y = d[1] * rs * g0.y + b0.y;
  x0.z = d[2] * rs * g0.z + b0.z; x0.w = d[3] * rs * g0.w + b0.w;
  x1.x = d[4] * rs * g1.x + b1.x; x1.y = d[5] * rs * g1.y + b1.y;
  x1.z = d[6] * rs * g1.z + b1.z; x1.w = d[7] * rs * g1.w + b1.w;
  *(float4*)pv = x0;
  *(float4*)(pv + 4) = x1;
  if (awbOut) {
    int b = (int)(row / M);
    int m = (int)(row - (long)b * M);
    float4 w0 = *(const float4*)(wNext + d0);
    float4 w1 = *(const float4*)(wNext + d0 + 4);
    *(bf16x8*)(awbOut + ((long)b * Mpad + m) * DIM + d0) =
        pack8(mul4(s0, w0), mul4(s1, w1));
  }
}

// =======================================================================
extern "C" void kernel_launch(void* const* d_in, const int* in_sizes, int n_in,
                              void* d_out, int out_size, void* d_ws, size_t ws_size,
                              hipStream_t stream) {
  (void)in_sizes; (void)n_in; (void)out_size; (void)ws_size;
  const int* tokens = (const int*)d_in[0];
  const float* embed = (const float*)d_in[1];
  const float* readout_w = (const float*)d_in[2];
  const float* readout_b = (const float*)d_in[3];
  const float* w_s = (const float*)d_in[4];
  const float* w_se = (const float*)d_in[5];
  const float* w_sc = (const float*)d_in[6];
  const float* w_s2e = (const float*)d_in[7];
  const float* w_e2s = (const float*)d_in[8];
  const float* w_s2c = (const float*)d_in[9];
  const float* w_c2s = (const float*)d_in[10];
  const float* ln_s_g = (const float*)d_in[11];
  const float* ln_s_b = (const float*)d_in[12];
  const float* ln_e_g = (const float*)d_in[13];
  const float* ln_e_b = (const float*)d_in[14];
  const float* ln_c_g = (const float*)d_in[15];
  const float* ln_c_b = (const float*)d_in[16];
  const float* pe_e[3] = {(const float*)d_in[17], (const float*)d_in[19], (const float*)d_in[21]};
  const float* pe_c[3] = {(const float*)d_in[18], (const float*)d_in[20], (const float*)d_in[22]};

  static const int NEXP[3] = {2151, 2253, 2458};
  static const int NCMP[3] = {1844, 1639, 1434};
  static const int NEXP_P[3] = {2176, 2304, 2560};
  static const int NCMP_P[3] = {1920, 1664, 1536};
  static const int LAYERS[3] = {2, 2, 1};
  static const float ALPHA[3][3] = {{0.3f, 0.25f, 0.15f}, {0.65f, 0.55f, 0.35f}, {1.0f, 0.9f, 0.8f}};

  const long SZ_S = 2L * SEQ * DIM;
  const long SZ_E = 2L * 2458 * DIM;
  const long SZ_C = 2L * 1844 * DIM;
  float* ws = (float*)d_ws;
  float* sS[2] = {ws, ws + SZ_S}; ws += 2 * SZ_S;
  float* sV[2] = {ws, ws + SZ_S}; ws += 2 * SZ_S;
  float* eS[2] = {ws, ws + SZ_E}; ws += 2 * SZ_E;
  float* eV[2] = {ws, ws + SZ_E}; ws += 2 * SZ_E;
  float* cS[2] = {ws, ws + SZ_C}; ws += 2 * SZ_C;
  float* cV[2] = {ws, ws + SZ_C}; ws += 2 * SZ_C;
  float* scores = ws; ws += 18000000;
  __bf16* bw = (__bf16*)ws;
  __bf16* sb = bw;      bw += 2L * 2048 * DIM;
  __bf16* eb = bw;      bw += 2L * 2560 * DIM;
  __bf16* cb = bw;      bw += 2L * 1920 * DIM;
  __bf16* awbS2e = bw;  bw += 2L * 2560 * DIM;
  __bf16* awbS2c = bw;  bw += 2L * 1920 * DIM;
  __bf16* awbSe = bw;   bw += 2L * 2560 * DIM;
  __bf16* awbSc = bw;   bw += 2L * 1920 * DIM;
  __bf16* awbE = bw;    bw += 2L * 2048 * DIM;
  __bf16* awbC = bw;    bw += 2L * 2048 * DIM;
  __bf16* valb = bw;    bw += 4096L * DIM;
  __bf16* rwT = bw;     bw += 32000L * DIM;

  auto cdiv = [](long a, long b) { return (int)((a + b - 1) / b); };

  k_embed<<<NB * SEQ, 128, 0, stream>>>(tokens, embed, sS[0], sV[0]);

  int cs = 0, li = 0;
  for (int st = 0; st < 3; ++st) {
    const int Ne = NEXP[st], Nc = NCMP[st];
    const int NeP = NEXP_P[st], NcP = NCMP_P[st];
    const float alpha = ALPHA[st][0], bs2b = ALPHA[st][1], bb2s = ALPHA[st][2];
    const float sc_x = 0.15f * bs2b * alpha;
    const float sc_b = 0.2f * alpha;
    const float sc_s = 0.15f * bb2s;
    int ce = 0, cc = 0;
    k_bcast2<<<cdiv((long)NB * NeP, 4), 256, 0, stream>>>(
        pe_e[st], eS[0], eV[0], eb, w_s2e + (long)li * DIM, awbS2e, Ne, NeP);
    k_bcast2<<<cdiv((long)NB * NcP, 4), 256, 0, stream>>>(
        pe_c[st], cS[0], cV[0], cb, w_s2c + (long)li * DIM, awbS2c, Nc, NcP);
    for (int l = 0; l < LAYERS[st]; ++l) {
      const bool lastOfStage = (l == LAYERS[st] - 1);
      const bool finalLayer = (st == 2);
      // 1. window prop
      k_window<<<NB * SEQ / 4, 256, 0, stream>>>(
          sS[cs], sV[cs], w_s + (long)li * DIM, sS[cs ^ 1], sV[cs ^ 1], sb,
          w_e2s + (long)li * DIM, w_c2s + (long)li * DIM, awbE, awbC);
      cs ^= 1;
      // 2+3 grouped GEMM, then merged topk pair (independent e/c)
      float* scores2 = scores + (long)NB * NeP * SEQ;
      {
        dim3 g(SEQ / 128, (NeP + NcP) / 128, NB);
        k_mfma_g2<<<g, 256, 0, stream>>>(awbS2e, sb, scores, NeP, SEQ, SEQ,
                                         awbS2c, sb, scores2, NcP, SEQ, SEQ);
      }
      {
        int nb1 = cdiv((long)NB * Ne, 4), nb2 = cdiv((long)NB * Nc, 4);
        k_topk2<<<nb1 + nb2, 256, 0, stream>>>(
            scores, NeP, SEQ, sS[cs], sV[cs], eS[ce], eV[ce], eS[ce ^ 1], eV[ce ^ 1],
            eb, NeP, w_se + (long)li * DIM, awbSe, Ne, SEQ, sc_x, nb1,
            scores2, NcP, SEQ, sS[cs], sV[cs], cS[cc], cV[cc], cS[cc ^ 1], cV[cc ^ 1],
            cb, NcP, w_sc + (long)li * DIM, awbSc, Nc, SEQ, sc_x);
        ce ^= 1;
        cc ^= 1;
      }
      // 4+5 grouped GEMM, then merged topk pair
      float* scores2b = scores + (long)NB * NeP * NeP;
      {
        dim3 g(NeP / 128, (NeP + NcP) / 128, NB);
        k_mfma_g2<<<g, 256, 0, stream>>>(awbSe, eb, scores, NeP, NeP, NeP,
                                         awbSc, cb, scores2b, NcP, NcP, NcP);
      }
      {
        int nb1 = cdiv((long)NB * Ne, 4), nb2 = cdiv((long)NB * Nc, 4);
        k_topk2<<<nb1 + nb2, 256, 0, stream>>>(
            scores, NeP, NeP, eS[ce], eV[ce], eS[ce], eV[ce], eS[ce ^ 1], eV[ce ^ 1],
            eb, NeP, nullptr, nullptr, Ne, Ne, sc_b, nb1,
            scores2b, NcP, NcP, cS[cc], cV[cc], cS[cc], cV[cc], cS[cc ^ 1], cV[cc ^ 1],
            cb, NcP, nullptr, nullptr, Nc, Nc, sc_b);
        ce ^= 1;
        cc ^= 1;
      }
      // 6a+6b grouped GEMM, then ONE merged e->s + c->s + stabilize kernel
      float* scores2c = scores + (long)NB * SEQ * NeP;
      {
        dim3 g(NeP / 128, (2 * SEQ) / 128, NB);
        k_mfma_g2<<<g, 256, 0, stream>>>(awbE, eb, scores, SEQ, NeP, NeP,
                                         awbC, cb, scores2c, SEQ, NcP, NcP);
      }
      k_topk_ec<<<NB * SEQ / 4, 256, 0, stream>>>(
          scores, NeP, eS[ce], eV[ce], Ne,
          scores2c, NcP, cS[cc], cV[cc], Nc,
          sS[cs], sV[cs], sS[cs ^ 1], sV[cs ^ 1],
          ln_s_g + (long)li * DIM, ln_s_b + (long)li * DIM,
          finalLayer ? valb : nullptr, sc_s);
      cs ^= 1;
      // 7. stabilize e/c (only when consumed) + fused next-layer step-2/3 A-panels
      if (!lastOfStage) {
        k_stab<<<cdiv((long)NB * Ne, 4), 256, 0, stream>>>(
            eS[ce], eV[ce], ln_e_g + (long)li * DIM, ln_e_b + (long)li * DIM,
            w_s2e + (long)(li + 1) * DIM, awbS2e, Ne, NeP);
        k_stab<<<cdiv((long)NB * Nc, 4), 256, 0, stream>>>(
            cS[cc], cV[cc], ln_c_g + (long)li * DIM, ln_c_b + (long)li * DIM,
            w_s2c + (long)(li + 1) * DIM, awbS2c, Nc, NcP);
      }
      ++li;
    }
  }
  // readout
  {
    dim3 g(1000, 16);
    dim3 blk(32, 8);
    k_transpose_rw<<<g, blk, 0, stream>>>(readout_w, rwT);
  }
  {
    dim3 g((NB * SEQ) / 128, 32000 / 128, 1);
    k_mfma_ro<<<g, 256, 0, stream>>>(valb, rwT, (float*)d_out, readout_b, NB * SEQ, 32000, 32000);
  }
}

// Round 17
// 1717.818 us; speedup vs baseline: 1.0444x; 1.0444x over previous
//
#include <hip/hip_runtime.h>
#include <hip/hip_bf16.h>
#include <math.h>

#define DIM 512
#define SEQ 2048
#define NB 2
#define NEG_INF (-1e30f)

typedef __bf16 bf16x8 __attribute__((ext_vector_type(8)));
typedef float f32x4 __attribute__((ext_vector_type(4)));

static __device__ __forceinline__ float wave_sum(float x) {
#pragma unroll
  for (int off = 32; off; off >>= 1) x += __shfl_xor(x, off, 64);
  return x;
}

static __device__ __forceinline__ bf16x8 pack8(float4 a, float4 b) {
  bf16x8 r;
  r[0] = (__bf16)a.x; r[1] = (__bf16)a.y; r[2] = (__bf16)a.z; r[3] = (__bf16)a.w;
  r[4] = (__bf16)b.x; r[5] = (__bf16)b.y; r[6] = (__bf16)b.z; r[7] = (__bf16)b.w;
  return r;
}

static __device__ __forceinline__ float4 mul4(float4 a, float4 b) {
  return make_float4(a.x * b.x, a.y * b.y, a.z * b.z, a.w * b.w);
}

static __device__ __forceinline__ void gload16(const void* g, void* l) {
  __builtin_amdgcn_global_load_lds((const __attribute__((address_space(1))) void*)g,
                                   (__attribute__((address_space(3))) void*)l, 16, 0, 0);
}

// top-4 select on one score row (scan loop form identical to topk_body's)
static __device__ __forceinline__ void topk_sel(const float* __restrict__ sc, int N, int lane,
                                                float rv[4], int ri[4]) {
  float v0 = NEG_INF, v1 = NEG_INF, v2 = NEG_INF, v3 = NEG_INF;
  int i0 = 0x7fffffff, i1 = 0x7fffffff, i2 = 0x7fffffff, i3 = 0x7fffffff;
  for (int s = lane; s < N; s += 64) {
    float x = sc[s];
    if (x > v3) {
      if (x > v0) { v3 = v2; i3 = i2; v2 = v1; i2 = i1; v1 = v0; i1 = i0; v0 = x; i0 = s; }
      else if (x > v1) { v3 = v2; i3 = i2; v2 = v1; i2 = i1; v1 = x; i1 = s; }
      else if (x > v2) { v3 = v2; i3 = i2; v2 = x; i2 = s; }
      else { v3 = x; i3 = s; }
    }
  }
  int ptr = 0;
#pragma unroll
  for (int r = 0; r < 4; ++r) {
    float cv = (ptr == 0) ? v0 : (ptr == 1) ? v1 : (ptr == 2) ? v2 : (ptr == 3) ? v3 : NEG_INF;
    int ci = (ptr == 0) ? i0 : (ptr == 1) ? i1 : (ptr == 2) ? i2 : (ptr == 3) ? i3 : 0x7fffffff;
    float bv = cv;
    int bi = ci;
#pragma unroll
    for (int off = 32; off; off >>= 1) {
      float ov = __shfl_xor(bv, off, 64);
      int oi = __shfl_xor(bi, off, 64);
      if (ov > bv || (ov == bv && oi < bi)) { bv = ov; bi = oi; }
    }
    rv[r] = bv;
    ri[r] = bi;
    if (bi == ci) ptr++;
  }
}

// ---------------- embed gather ----------------
__global__ __launch_bounds__(128) void k_embed(const int* __restrict__ tok,
                                               const float* __restrict__ emb,
                                               float* __restrict__ sS,
                                               float* __restrict__ sV) {
  long row = blockIdx.x;
  int t = tok[row];
  const float4* src = (const float4*)(emb + (long)t * DIM);
  float4* a = (float4*)(sS + row * DIM);
  float4* b = (float4*)(sV + row * DIM);
  int i = threadIdx.x;
  float4 v = src[i];
  a[i] = v;
  b[i] = v;
}

// ---- broadcast pe -> f32 state/val + bf16 mirror + fused first-layer A-panel ----
__global__ __launch_bounds__(256) void k_bcast2(const float* __restrict__ pe,
                                                float* __restrict__ s, float* __restrict__ v,
                                                __bf16* __restrict__ mb,
                                                const float* __restrict__ wA,
                                                __bf16* __restrict__ awbOut,
                                                int N, int Npad) {
  int wid = threadIdx.x >> 6, lane = threadIdx.x & 63;
  long row = (long)blockIdx.x * 4 + wid;
  if (row >= (long)NB * Npad) return;
  int b = (int)(row / Npad), m = (int)(row % Npad);
  int d0 = lane * 8;
  if (m < N) {
    float4 x0 = *(const float4*)(pe + (long)m * DIM + d0);
    float4 x1 = *(const float4*)(pe + (long)m * DIM + d0 + 4);
    long fo = ((long)b * N + m) * DIM + d0;
    *(float4*)(s + fo) = x0; *(float4*)(s + fo + 4) = x1;
    *(float4*)(v + fo) = x0; *(float4*)(v + fo + 4) = x1;
    *(bf16x8*)(mb + row * DIM + d0) = pack8(x0, x1);
    float4 w0 = *(const float4*)(wA + d0);
    float4 w1 = *(const float4*)(wA + d0 + 4);
    *(bf16x8*)(awbOut + row * DIM + d0) = pack8(mul4(x0, w0), mul4(x1, w1));
  } else {
    bf16x8 z;
#pragma unroll
    for (int i = 0; i < 8; ++i) z[i] = (__bf16)0.f;
    *(bf16x8*)(mb + row * DIM + d0) = z;
    *(bf16x8*)(awbOut + row * DIM + d0) = z;
  }
}

// ---------------- readout_w transpose+cvt ----------------
__global__ __launch_bounds__(256) void k_transpose_rw(const float* __restrict__ in,
                                                      __bf16* __restrict__ out) {
  __shared__ float t[32][33];
  int tx = threadIdx.x, ty = threadIdx.y;
  int n0 = blockIdx.x * 32, k0 = blockIdx.y * 32;
#pragma unroll
  for (int i = 0; i < 4; ++i)
    t[ty + i * 8][tx] = in[(long)(k0 + ty + i * 8) * 32000 + n0 + tx];
  __syncthreads();
#pragma unroll
  for (int i = 0; i < 4; ++i)
    out[(long)(n0 + ty + i * 8) * DIM + k0 + tx] = (__bf16)t[tx][ty + i * 8];
}

// ---- causal window-4 propagation; emits bf16 mirrors: s, s*wE, s*wC ----
__global__ __launch_bounds__(256) void k_window(const float* __restrict__ sS,
                                                const float* __restrict__ sV,
                                                const float* __restrict__ w,
                                                float* __restrict__ oS,
                                                float* __restrict__ oV,
                                                __bf16* __restrict__ oSb,
                                                const float* __restrict__ wE,
                                                const float* __restrict__ wC,
                                                __bf16* __restrict__ awbE,
                                                __bf16* __restrict__ awbC) {
  int wid = threadIdx.x >> 6, lane = threadIdx.x & 63;
  long row = (long)blockIdx.x * 4 + wid;
  int i = (int)(row & (SEQ - 1));
  int d0 = lane * 8;
  const float* ps = sS + row * DIM + d0;
  const float* pv = sV + row * DIM + d0;
  float4 s0 = *(const float4*)ps;
  float4 s1 = *(const float4*)(ps + 4);
  float4 w0 = *(const float4*)(w + d0);
  float4 w1 = *(const float4*)(w + d0 + 4);
  float4 aw0 = mul4(s0, w0);
  float4 aw1 = mul4(s1, w1);
  float4 nS0[4], nS1[4], nV0[4], nV1[4];
  float sc[4];
#pragma unroll
  for (int k = 0; k < 4; ++k) {
    bool valid = (i >= k + 1);
    const float* qs = ps - (long)(k + 1) * DIM;
    const float* qv = pv - (long)(k + 1) * DIM;
    if (valid) {
      nS0[k] = *(const float4*)qs;
      nS1[k] = *(const float4*)(qs + 4);
      nV0[k] = *(const float4*)qv;
      nV1[k] = *(const float4*)(qv + 4);
    } else {
      nS0[k] = make_float4(0.f, 0.f, 0.f, 0.f);
      nS1[k] = nS0[k]; nV0[k] = nS0[k]; nV1[k] = nS0[k];
    }
    sc[k] = aw0.x * nS0[k].x + aw0.y * nS0[k].y + aw0.z * nS0[k].z + aw0.w * nS0[k].w +
            aw1.x * nS1[k].x + aw1.y * nS1[k].y + aw1.z * nS1[k].z + aw1.w * nS1[k].w;
  }
#pragma unroll
  for (int k = 0; k < 4; ++k) sc[k] = wave_sum(sc[k]);
  float m = NEG_INF;
#pragma unroll
  for (int k = 0; k < 4; ++k)
    if (i >= k + 1 && sc[k] > m) m = sc[k];
  float p[4];
  float Z = 0.f;
#pragma unroll
  for (int k = 0; k < 4; ++k) {
    p[k] = (i >= k + 1) ? expf(sc[k] - m) : 0.f;
    Z += p[k];
  }
  float invZ = (Z > 0.f) ? (1.f / Z) : 0.f;
  float4 v0 = *(const float4*)pv;
  float4 v1 = *(const float4*)(pv + 4);
  float4 os0 = s0, os1 = s1, ov0 = v0, ov1 = v1;
#pragma unroll
  for (int k = 0; k < 4; ++k) {
    float c = 0.25f * p[k] * invZ;
    os0.x += c * nS0[k].x; os0.y += c * nS0[k].y; os0.z += c * nS0[k].z; os0.w += c * nS0[k].w;
    os1.x += c * nS1[k].x; os1.y += c * nS1[k].y; os1.z += c * nS1[k].z; os1.w += c * nS1[k].w;
    ov0.x += c * nV0[k].x; ov0.y += c * nV0[k].y; ov0.z += c * nV0[k].z; ov0.w += c * nV0[k].w;
    ov1.x += c * nV1[k].x; ov1.y += c * nV1[k].y; ov1.z += c * nV1[k].z; ov1.w += c * nV1[k].w;
  }
  *(float4*)(oS + row * DIM + d0) = os0;
  *(float4*)(oS + row * DIM + d0 + 4) = os1;
  *(float4*)(oV + row * DIM + d0) = ov0;
  *(float4*)(oV + row * DIM + d0 + 4) = ov1;
  *(bf16x8*)(oSb + row * DIM + d0) = pack8(os0, os1);
  float4 we0 = *(const float4*)(wE + d0);
  float4 we1 = *(const float4*)(wE + d0 + 4);
  *(bf16x8*)(awbE + row * DIM + d0) = pack8(mul4(os0, we0), mul4(os1, we1));
  float4 wc0 = *(const float4*)(wC + d0);
  float4 wc1 = *(const float4*)(wC + d0 + 4);
  *(bf16x8*)(awbC + row * DIM + d0) = pack8(mul4(os0, wc0), mul4(os1, wc1));
}

// ------ grouped score GEMM: two sub-GEMMs per dispatch, 3-deep ring + counted vmcnt ------
__global__ __launch_bounds__(256) void k_mfma_g2(
    const __bf16* __restrict__ A1, const __bf16* __restrict__ B1, float* __restrict__ C1,
    int Mpad1, int Npad1, int ldc1,
    const __bf16* __restrict__ A2, const __bf16* __restrict__ B2, float* __restrict__ C2,
    int Mpad2, int Npad2, int ldc2) {
  const __bf16* A; const __bf16* Bm; float* C;
  int Mpad, Npad, ldc;
  long my;
  int M1b = Mpad1 >> 7;
  if ((int)blockIdx.y < M1b) {
    A = A1; Bm = B1; C = C1; Mpad = Mpad1; Npad = Npad1; ldc = ldc1; my = blockIdx.y;
  } else {
    A = A2; Bm = B2; C = C2; Mpad = Mpad2; Npad = Npad2; ldc = ldc2; my = blockIdx.y - M1b;
  }
  const long n0 = (long)blockIdx.x * 128;
  if (n0 >= Npad) return;
  const long m0 = my * 128;

  __shared__ __align__(1024) char lds[49152];
  const int tid = threadIdx.x;
  const int wid = tid >> 6, lane = tid & 63;
  const int b = blockIdx.z;
  const char* Ab = (const char*)(A + ((long)b * Mpad + m0) * DIM);
  const char* Bb = (const char*)(Bm + ((long)b * Npad + n0) * DIM);
  const int mw = (wid >> 1) * 64, nw = (wid & 1) * 64;

  int srow[2], scol[2], dofs[2];
#pragma unroll
  for (int is = 0; is < 2; ++is) {
    int d = is * 4096 + wid * 1024 + lane * 16;
    int s = d ^ (((d >> 8) & 3) << 4);
    srow[is] = s >> 6;
    scol[is] = s & 63;
    dofs[is] = is * 4096 + wid * 1024;
  }
  int aoff[4], boff[4];
#pragma unroll
  for (int f = 0; f < 4; ++f) {
    int rowA = mw + f * 16 + (lane & 15);
    int byA = rowA * 64 + (lane >> 4) * 16;
    aoff[f] = byA ^ (((byA >> 8) & 3) << 4);
    int rowB = nw + f * 16 + (lane & 15);
    int byB = rowB * 64 + (lane >> 4) * 16;
    boff[f] = (byB ^ (((byB >> 8) & 3) << 4)) + 8192;
  }
  auto stage = [&](int buf, int k0) {
#pragma unroll
    for (int is = 0; is < 2; ++is) {
      gload16(Ab + (long)srow[is] * (DIM * 2) + k0 * 2 + scol[is], lds + buf * 16384 + dofs[is]);
      gload16(Bb + (long)srow[is] * (DIM * 2) + k0 * 2 + scol[is], lds + buf * 16384 + 8192 + dofs[is]);
    }
  };

  f32x4 acc[4][4] = {};
  stage(0, 0);
  stage(1, 32);
#pragma unroll
  for (int t = 0; t < 16; ++t) {
    if (t <= 13) {
      stage((t + 2) % 3, (t + 2) * 32);
      asm volatile("s_waitcnt vmcnt(8)" ::: "memory");
    } else if (t == 14) {
      asm volatile("s_waitcnt vmcnt(4)" ::: "memory");
    } else {
      asm volatile("s_waitcnt vmcnt(0)" ::: "memory");
    }
    __builtin_amdgcn_s_barrier();
    const char* base = lds + (t % 3) * 16384;
    bf16x8 af[4], bf[4];
#pragma unroll
    for (int f = 0; f < 4; ++f) {
      af[f] = *(const bf16x8*)(base + aoff[f]);
      bf[f] = *(const bf16x8*)(base + boff[f]);
    }
    asm volatile("s_waitcnt lgkmcnt(0)" ::: "memory");
    __builtin_amdgcn_sched_barrier(0);
    __builtin_amdgcn_s_barrier();
#pragma unroll
    for (int i = 0; i < 4; ++i)
#pragma unroll
      for (int j = 0; j < 4; ++j)
        acc[i][j] = __builtin_amdgcn_mfma_f32_16x16x32_bf16(af[i], bf[j], acc[i][j], 0, 0, 0);
  }
  float* Cb = C + ((long)b * Mpad + m0) * ldc + n0;
#pragma unroll
  for (int i = 0; i < 4; ++i) {
    int mrow = mw + i * 16 + (lane >> 4) * 4;
#pragma unroll
    for (int r = 0; r < 4; ++r) {
      long moff = (long)(mrow + r) * ldc;
#pragma unroll
      for (int j = 0; j < 4; ++j) {
        int ncol = nw + j * 16 + (lane & 15);
        Cb[moff + ncol] = acc[i][j][r];
      }
    }
  }
}

// -------- readout GEMM: 2-phase, XCD-chunked swizzle, NT stores --------
__global__ __launch_bounds__(256) void k_mfma_ro(const __bf16* __restrict__ A,
                                                 const __bf16* __restrict__ Bm,
                                                 float* __restrict__ C,
                                                 const float* __restrict__ bias,
                                                 int Mpad, int Npad, int ldc) {
  __shared__ __align__(1024) char lds[32768];
  const int tid = threadIdx.x;
  const int wid = tid >> 6, lane = tid & 63;
  long hw = (long)blockIdx.y * gridDim.x + blockIdx.x;
  long nwg = (long)gridDim.x * gridDim.y;
  long cpx = nwg >> 3;
  long l = (hw & 7) * cpx + (hw >> 3);
  const long m0 = (l % gridDim.x) * 128;
  const long n0 = (l / gridDim.x) * 128;
  const char* Ab = (const char*)(A + m0 * DIM);
  const char* Bb = (const char*)(Bm + n0 * DIM);
  const int mw = (wid >> 1) * 64, nw = (wid & 1) * 64;

  int srow[2], scol[2], dofs[2];
#pragma unroll
  for (int is = 0; is < 2; ++is) {
    int d = is * 4096 + wid * 1024 + lane * 16;
    int s = d ^ (((d >> 8) & 3) << 4);
    srow[is] = s >> 6;
    scol[is] = s & 63;
    dofs[is] = is * 4096 + wid * 1024;
  }
  int aoff[4], boff[4];
#pragma unroll
  for (int f = 0; f < 4; ++f) {
    int rowA = mw + f * 16 + (lane & 15);
    int byA = rowA * 64 + (lane >> 4) * 16;
    aoff[f] = byA ^ (((byA >> 8) & 3) << 4);
    int rowB = nw + f * 16 + (lane & 15);
    int byB = rowB * 64 + (lane >> 4) * 16;
    boff[f] = (byB ^ (((byB >> 8) & 3) << 4)) + 8192;
  }
  auto stage = [&](int buf, int k0) {
#pragma unroll
    for (int is = 0; is < 2; ++is) {
      gload16(Ab + (long)srow[is] * (DIM * 2) + k0 * 2 + scol[is], lds + buf * 16384 + dofs[is]);
      gload16(Bb + (long)srow[is] * (DIM * 2) + k0 * 2 + scol[is], lds + buf * 16384 + 8192 + dofs[is]);
    }
  };

  f32x4 acc[4][4] = {};
  stage(0, 0);
  asm volatile("s_waitcnt vmcnt(0)" ::: "memory");
  __syncthreads();
  int cur = 0;
  for (int k0 = 0; k0 < DIM; k0 += 32) {
    const bool more = (k0 + 32 < DIM);
    if (more) stage(cur ^ 1, k0 + 32);
    const char* base = lds + cur * 16384;
    bf16x8 af[4], bf[4];
#pragma unroll
    for (int f = 0; f < 4; ++f) {
      af[f] = *(const bf16x8*)(base + aoff[f]);
      bf[f] = *(const bf16x8*)(base + boff[f]);
    }
#pragma unroll
    for (int i = 0; i < 4; ++i)
#pragma unroll
      for (int j = 0; j < 4; ++j)
        acc[i][j] = __builtin_amdgcn_mfma_f32_16x16x32_bf16(af[i], bf[j], acc[i][j], 0, 0, 0);
    if (more) {
      asm volatile("s_waitcnt vmcnt(0)" ::: "memory");
      __syncthreads();
      cur ^= 1;
    }
  }
  float* Cb = C + m0 * ldc + n0;
  float bv[4];
#pragma unroll
  for (int j = 0; j < 4; ++j) bv[j] = bias[n0 + nw + j * 16 + (lane & 15)];
#pragma unroll
  for (int i = 0; i < 4; ++i) {
    int mrow = mw + i * 16 + (lane >> 4) * 4;
#pragma unroll
    for (int r = 0; r < 4; ++r) {
      long moff = (long)(mrow + r) * ldc;
#pragma unroll
      for (int j = 0; j < 4; ++j) {
        int ncol = nw + j * 16 + (lane & 15);
        __builtin_nontemporal_store(acc[i][j][r] + bv[j], &Cb[moff + ncol]);
      }
    }
  }
}

// ---- top-4 + softmax + gather + update body (scan loop UNCHANGED) ----
static __device__ __forceinline__ void topk_body(
    long blk,
    const float* __restrict__ scores, int Mpad, int ldc,
    const float* __restrict__ srcS, const float* __restrict__ srcV,
    const float* __restrict__ baseS, const float* __restrict__ baseV,
    float* __restrict__ outS, float* __restrict__ outV,
    __bf16* __restrict__ outSb, int MpadMir,
    const float* __restrict__ wNext, __bf16* __restrict__ outAw,
    const float* __restrict__ lnG, const float* __restrict__ lnB,
    __bf16* __restrict__ outValb,
    int M, int N, float scale) {
  int wid = threadIdx.x >> 6, lane = threadIdx.x & 63;
  long row = blk * 4 + wid;
  long total = (long)NB * M;
  if (row >= total) return;
  int b = (int)(row / M);
  int m = (int)(row - (long)b * M);
  float rv[4];
  int ri[4];
  topk_sel(scores + ((long)b * Mpad + m) * ldc, N, lane, rv, ri);
  float p0 = 1.f, p1 = expf(rv[1] - rv[0]), p2 = expf(rv[2] - rv[0]), p3 = expf(rv[3] - rv[0]);
  float invZ = 1.f / (p0 + p1 + p2 + p3);
  p0 *= invZ; p1 *= invZ; p2 *= invZ; p3 *= invZ;
  int d0 = lane * 8;
  long sb = (long)b * N;
  const float* gs0 = srcS + (sb + ri[0]) * DIM + d0;
  const float* gs1 = srcS + (sb + ri[1]) * DIM + d0;
  const float* gs2 = srcS + (sb + ri[2]) * DIM + d0;
  const float* gs3 = srcS + (sb + ri[3]) * DIM + d0;
  const float* gv0 = srcV + (sb + ri[0]) * DIM + d0;
  const float* gv1 = srcV + (sb + ri[1]) * DIM + d0;
  const float* gv2 = srcV + (sb + ri[2]) * DIM + d0;
  const float* gv3 = srcV + (sb + ri[3]) * DIM + d0;
  long ro = row * DIM + d0;
  float4 osv[2], qsv[2];
#pragma unroll
  for (int h = 0; h < 2; ++h) {
    float4 x0 = *(const float4*)(gs0 + h * 4);
    float4 x1 = *(const float4*)(gs1 + h * 4);
    float4 x2 = *(const float4*)(gs2 + h * 4);
    float4 x3 = *(const float4*)(gs3 + h * 4);
    float4 o = *(const float4*)(baseS + ro + h * 4);
    o.x += scale * (p0 * x0.x + p1 * x1.x + p2 * x2.x + p3 * x3.x);
    o.y += scale * (p0 * x0.y + p1 * x1.y + p2 * x2.y + p3 * x3.y);
    o.z += scale * (p0 * x0.z + p1 * x1.z + p2 * x2.z + p3 * x3.z);
    o.w += scale * (p0 * x0.w + p1 * x1.w + p2 * x2.w + p3 * x3.w);
    osv[h] = o;
    float4 y0 = *(const float4*)(gv0 + h * 4);
    float4 y1 = *(const float4*)(gv1 + h * 4);
    float4 y2 = *(const float4*)(gv2 + h * 4);
    float4 y3 = *(const float4*)(gv3 + h * 4);
    float4 q = *(const float4*)(baseV + ro + h * 4);
    q.x += scale * (p0 * y0.x + p1 * y1.x + p2 * y2.x + p3 * y3.x);
    q.y += scale * (p0 * y0.y + p1 * y1.y + p2 * y2.y + p3 * y3.y);
    q.z += scale * (p0 * y0.z + p1 * y1.z + p2 * y2.z + p3 * y3.z);
    q.w += scale * (p0 * y0.w + p1 * y1.w + p2 * y2.w + p3 * y3.w);
    qsv[h] = q;
  }
  if (lnG) {
    osv[0].x = tanhf(osv[0].x); osv[0].y = tanhf(osv[0].y);
    osv[0].z = tanhf(osv[0].z); osv[0].w = tanhf(osv[0].w);
    osv[1].x = tanhf(osv[1].x); osv[1].y = tanhf(osv[1].y);
    osv[1].z = tanhf(osv[1].z); osv[1].w = tanhf(osv[1].w);
    float sum = qsv[0].x + qsv[0].y + qsv[0].z + qsv[0].w +
                qsv[1].x + qsv[1].y + qsv[1].z + qsv[1].w;
    sum = wave_sum(sum);
    float mu = sum * (1.f / DIM);
    float d[8] = {qsv[0].x - mu, qsv[0].y - mu, qsv[0].z - mu, qsv[0].w - mu,
                  qsv[1].x - mu, qsv[1].y - mu, qsv[1].z - mu, qsv[1].w - mu};
    float ss = d[0]*d[0] + d[1]*d[1] + d[2]*d[2] + d[3]*d[3] +
               d[4]*d[4] + d[5]*d[5] + d[6]*d[6] + d[7]*d[7];
    ss = wave_sum(ss);
    float rs = rsqrtf(ss * (1.f / DIM) + 1e-5f);
    float4 g0 = *(const float4*)(lnG + d0);
    float4 g1 = *(const float4*)(lnG + d0 + 4);
    float4 b0 = *(const float4*)(lnB + d0);
    float4 b1 = *(const float4*)(lnB + d0 + 4);
    qsv[0].x = d[0] * rs * g0.x + b0.x; qsv[0].y = d[1] * rs * g0.y + b0.y;
    qsv[0].z = d[2] * rs * g0.z + b0.z; qsv[0].w = d[3] * rs * g0.w + b0.w;
    qsv[1].x = d[4] * rs * g1.x + b1.x; qsv[1].y = d[5] * rs * g1.y + b1.y;
    qsv[1].z = d[6] * rs * g1.z + b1.z; qsv[1].w = d[7] * rs * g1.w + b1.w;
  }
#pragma unroll
  for (int h = 0; h < 2; ++h) {
    *(float4*)(outS + ro + h * 4) = osv[h];
    *(float4*)(outV + ro + h * 4) = qsv[h];
  }
  if (outSb) {
    *(bf16x8*)(outSb + ((long)b * MpadMir + m) * DIM + d0) = pack8(osv[0], osv[1]);
  }
  if (outAw) {
    float4 w0 = *(const float4*)(wNext + d0);
    float4 w1 = *(const float4*)(wNext + d0 + 4);
    *(bf16x8*)(outAw + ((long)b * MpadMir + m) * DIM + d0) =
        pack8(mul4(osv[0], w0), mul4(osv[1], w1));
  }
  if (outValb) {
    *(bf16x8*)(outValb + ro) = pack8(qsv[0], qsv[1]);
  }
}

// single-problem top-k (used for dependent steps 6a/6b)
__global__ __launch_bounds__(256) void k_topk_update(
    const float* __restrict__ scores, int Mpad, int ldc,
    const float* __restrict__ srcS, const float* __restrict__ srcV,
    const float* __restrict__ baseS, const float* __restrict__ baseV,
    float* __restrict__ outS, float* __restrict__ outV,
    __bf16* __restrict__ outSb, int MpadMir,
    const float* __restrict__ wNext, __bf16* __restrict__ outAw,
    const float* __restrict__ lnG, const float* __restrict__ lnB,
    __bf16* __restrict__ outValb,
    int M, int N, float scale) {
  topk_body(blockIdx.x, scores, Mpad, ldc, srcS, srcV, baseS, baseV, outS, outV,
            outSb, MpadMir, wNext, outAw, lnG, lnB, outValb, M, N, scale);
}

// merged pair of INDEPENDENT top-k problems (e and c) in one dispatch
__global__ __launch_bounds__(256) void k_topk2(
    const float* __restrict__ sc1, int Mpad1, int ldc1,
    const float* __restrict__ srcS1, const float* __restrict__ srcV1,
    const float* __restrict__ baseS1, const float* __restrict__ baseV1,
    float* __restrict__ outS1, float* __restrict__ outV1,
    __bf16* __restrict__ outSb1, int MpadMir1,
    const float* __restrict__ wNext1, __bf16* __restrict__ outAw1,
    int M1, int N1, float scale1, int nblk1,
    const float* __restrict__ sc2, int Mpad2, int ldc2,
    const float* __restrict__ srcS2, const float* __restrict__ srcV2,
    const float* __restrict__ baseS2, const float* __restrict__ baseV2,
    float* __restrict__ outS2, float* __restrict__ outV2,
    __bf16* __restrict__ outSb2, int MpadMir2,
    const float* __restrict__ wNext2, __bf16* __restrict__ outAw2,
    int M2, int N2, float scale2) {
  if ((int)blockIdx.x < nblk1) {
    topk_body(blockIdx.x, sc1, Mpad1, ldc1, srcS1, srcV1, baseS1, baseV1, outS1, outV1,
              outSb1, MpadMir1, wNext1, outAw1, nullptr, nullptr, nullptr, M1, N1, scale1);
  } else {
    topk_body((long)blockIdx.x - nblk1, sc2, Mpad2, ldc2, srcS2, srcV2, baseS2, baseV2,
              outS2, outV2, outSb2, MpadMir2, wNext2, outAw2, nullptr, nullptr, nullptr,
              M2, N2, scale2);
  }
}

// ---- stabilize (e/c, non-stage-final layers) + fused next-layer s->B A-panel emit ----
__global__ __launch_bounds__(256) void k_stab(float* __restrict__ state,
                                              float* __restrict__ val,
                                              const float* __restrict__ g,
                                              const float* __restrict__ beta,
                                              const float* __restrict__ wNext,
                                              __bf16* __restrict__ awbOut,
                                              int M, int Mpad) {
  int wid = threadIdx.x >> 6, lane = threadIdx.x & 63;
  long row = (long)blockIdx.x * 4 + wid;
  if (row >= (long)NB * M) return;
  int d0 = lane * 8;
  float* ps = state + row * DIM + d0;
  float4 s0 = *(float4*)ps;
  float4 s1 = *(float4*)(ps + 4);
  s0.x = tanhf(s0.x); s0.y = tanhf(s0.y); s0.z = tanhf(s0.z); s0.w = tanhf(s0.w);
  s1.x = tanhf(s1.x); s1.y = tanhf(s1.y); s1.z = tanhf(s1.z); s1.w = tanhf(s1.w);
  *(float4*)ps = s0;
  *(float4*)(ps + 4) = s1;
  float* pv = val + row * DIM + d0;
  float4 x0 = *(float4*)pv;
  float4 x1 = *(float4*)(pv + 4);
  float sum = x0.x + x0.y + x0.z + x0.w + x1.x + x1.y + x1.z + x1.w;
  sum = wave_sum(sum);
  float mu = sum * (1.f / DIM);
  float d[8] = {x0.x - mu, x0.y - mu, x0.z - mu, x0.w - mu,
                x1.x - mu, x1.y - mu, x1.z - mu, x1.w - mu};
  float ss = d[0]*d[0] + d[1]*d[1] + d[2]*d[2] + d[3]*d[3] + d[4]*d[4] + d[5]*d[5] + d[6]*d[6] + d[7]*d[7];
  ss = wave_sum(ss);
  float rs = rsqrtf(ss * (1.f / DIM) + 1e-5f);
  float4 g0 = *(const float4*)(g + d0);
  float4 g1 = *(const float4*)(g + d0 + 4);
  float4 b0 = *(const float4*)(beta + d0);
  float4 b1 = *(const float4*)(beta + d0 + 4);
  x0.x = d[0] * rs * g0.x + b0.x; x0.y = d[1] * rs * g0.y + b0.y;
  x0.z = d[2] * rs * g0.z + b0.z; x0.w = d[3] * rs * g0.w + b0.w;
  x1.x = d[4] * rs * g1.x + b1.x; x1.y = d[5] * rs * g1.y + b1.y;
  x1.z = d[6] * rs * g1.z + b1.z; x1.w = d[7] * rs * g1.w + b1.w;
  *(float4*)pv = x0;
  *(float4*)(pv + 4) = x1;
  if (awbOut) {
    int b = (int)(row / M);
    int m = (int)(row - (long)b * M);
    float4 w0 = *(const float4*)(wNext + d0);
    float4 w1 = *(const float4*)(wNext + d0 + 4);
    *(bf16x8*)(awbOut + ((long)b * Mpad + m) * DIM + d0) =
        pack8(mul4(s0, w0), mul4(s1, w1));
  }
}

// =======================================================================
extern "C" void kernel_launch(void* const* d_in, const int* in_sizes, int n_in,
                              void* d_out, int out_size, void* d_ws, size_t ws_size,
                              hipStream_t stream) {
  (void)in_sizes; (void)n_in; (void)out_size; (void)ws_size;
  const int* tokens = (const int*)d_in[0];
  const float* embed = (const float*)d_in[1];
  const float* readout_w = (const float*)d_in[2];
  const float* readout_b = (const float*)d_in[3];
  const float* w_s = (const float*)d_in[4];
  const float* w_se = (const float*)d_in[5];
  const float* w_sc = (const float*)d_in[6];
  const float* w_s2e = (const float*)d_in[7];
  const float* w_e2s = (const float*)d_in[8];
  const float* w_s2c = (const float*)d_in[9];
  const float* w_c2s = (const float*)d_in[10];
  const float* ln_s_g = (const float*)d_in[11];
  const float* ln_s_b = (const float*)d_in[12];
  const float* ln_e_g = (const float*)d_in[13];
  const float* ln_e_b = (const float*)d_in[14];
  const float* ln_c_g = (const float*)d_in[15];
  const float* ln_c_b = (const float*)d_in[16];
  const float* pe_e[3] = {(const float*)d_in[17], (const float*)d_in[19], (const float*)d_in[21]};
  const float* pe_c[3] = {(const float*)d_in[18], (const float*)d_in[20], (const float*)d_in[22]};

  static const int NEXP[3] = {2151, 2253, 2458};
  static const int NCMP[3] = {1844, 1639, 1434};
  static const int NEXP_P[3] = {2176, 2304, 2560};
  static const int NCMP_P[3] = {1920, 1664, 1536};
  static const int LAYERS[3] = {2, 2, 1};
  static const float ALPHA[3][3] = {{0.3f, 0.25f, 0.15f}, {0.65f, 0.55f, 0.35f}, {1.0f, 0.9f, 0.8f}};

  const long SZ_S = 2L * SEQ * DIM;
  const long SZ_E = 2L * 2458 * DIM;
  const long SZ_C = 2L * 1844 * DIM;
  float* ws = (float*)d_ws;
  float* sS[2] = {ws, ws + SZ_S}; ws += 2 * SZ_S;
  float* sV[2] = {ws, ws + SZ_S}; ws += 2 * SZ_S;
  float* eS[2] = {ws, ws + SZ_E}; ws += 2 * SZ_E;
  float* eV[2] = {ws, ws + SZ_E}; ws += 2 * SZ_E;
  float* cS[2] = {ws, ws + SZ_C}; ws += 2 * SZ_C;
  float* cV[2] = {ws, ws + SZ_C}; ws += 2 * SZ_C;
  float* scores = ws; ws += 18000000;
  __bf16* bw = (__bf16*)ws;
  __bf16* sb = bw;      bw += 2L * 2048 * DIM;
  __bf16* eb = bw;      bw += 2L * 2560 * DIM;
  __bf16* cb = bw;      bw += 2L * 1920 * DIM;
  __bf16* awbS2e = bw;  bw += 2L * 2560 * DIM;
  __bf16* awbS2c = bw;  bw += 2L * 1920 * DIM;
  __bf16* awbSe = bw;   bw += 2L * 2560 * DIM;
  __bf16* awbSc = bw;   bw += 2L * 1920 * DIM;
  __bf16* awbE = bw;    bw += 2L * 2048 * DIM;
  __bf16* awbC = bw;    bw += 2L * 2048 * DIM;
  __bf16* valb = bw;    bw += 4096L * DIM;
  __bf16* rwT = bw;     bw += 32000L * DIM;

  auto cdiv = [](long a, long b) { return (int)((a + b - 1) / b); };

  k_embed<<<NB * SEQ, 128, 0, stream>>>(tokens, embed, sS[0], sV[0]);

  int cs = 0, li = 0;
  for (int st = 0; st < 3; ++st) {
    const int Ne = NEXP[st], Nc = NCMP[st];
    const int NeP = NEXP_P[st], NcP = NCMP_P[st];
    const float alpha = ALPHA[st][0], bs2b = ALPHA[st][1], bb2s = ALPHA[st][2];
    const float sc_x = 0.15f * bs2b * alpha;
    const float sc_b = 0.2f * alpha;
    const float sc_s = 0.15f * bb2s;
    int ce = 0, cc = 0;
    k_bcast2<<<cdiv((long)NB * NeP, 4), 256, 0, stream>>>(
        pe_e[st], eS[0], eV[0], eb, w_s2e + (long)li * DIM, awbS2e, Ne, NeP);
    k_bcast2<<<cdiv((long)NB * NcP, 4), 256, 0, stream>>>(
        pe_c[st], cS[0], cV[0], cb, w_s2c + (long)li * DIM, awbS2c, Nc, NcP);
    for (int l = 0; l < LAYERS[st]; ++l) {
      const bool lastOfStage = (l == LAYERS[st] - 1);
      const bool finalLayer = (st == 2);
      // 1. window prop
      k_window<<<NB * SEQ / 4, 256, 0, stream>>>(
          sS[cs], sV[cs], w_s + (long)li * DIM, sS[cs ^ 1], sV[cs ^ 1], sb,
          w_e2s + (long)li * DIM, w_c2s + (long)li * DIM, awbE, awbC);
      cs ^= 1;
      // 2+3 grouped GEMM, then merged topk pair (independent e/c)
      float* scores2 = scores + (long)NB * NeP * SEQ;
      {
        dim3 g(SEQ / 128, (NeP + NcP) / 128, NB);
        k_mfma_g2<<<g, 256, 0, stream>>>(awbS2e, sb, scores, NeP, SEQ, SEQ,
                                         awbS2c, sb, scores2, NcP, SEQ, SEQ);
      }
      {
        int nb1 = cdiv((long)NB * Ne, 4), nb2 = cdiv((long)NB * Nc, 4);
        k_topk2<<<nb1 + nb2, 256, 0, stream>>>(
            scores, NeP, SEQ, sS[cs], sV[cs], eS[ce], eV[ce], eS[ce ^ 1], eV[ce ^ 1],
            eb, NeP, w_se + (long)li * DIM, awbSe, Ne, SEQ, sc_x, nb1,
            scores2, NcP, SEQ, sS[cs], sV[cs], cS[cc], cV[cc], cS[cc ^ 1], cV[cc ^ 1],
            cb, NcP, w_sc + (long)li * DIM, awbSc, Nc, SEQ, sc_x);
        ce ^= 1;
        cc ^= 1;
      }
      // 4+5 grouped GEMM, then merged topk pair
      float* scores2b = scores + (long)NB * NeP * NeP;
      {
        dim3 g(NeP / 128, (NeP + NcP) / 128, NB);
        k_mfma_g2<<<g, 256, 0, stream>>>(awbSe, eb, scores, NeP, NeP, NeP,
                                         awbSc, cb, scores2b, NcP, NcP, NcP);
      }
      {
        int nb1 = cdiv((long)NB * Ne, 4), nb2 = cdiv((long)NB * Nc, 4);
        k_topk2<<<nb1 + nb2, 256, 0, stream>>>(
            scores, NeP, NeP, eS[ce], eV[ce], eS[ce], eV[ce], eS[ce ^ 1], eV[ce ^ 1],
            eb, NeP, nullptr, nullptr, Ne, Ne, sc_b, nb1,
            scores2b, NcP, NcP, cS[cc], cV[cc], cS[cc], cV[cc], cS[cc ^ 1], cV[cc ^ 1],
            cb, NcP, nullptr, nullptr, Nc, Nc, sc_b);
        ce ^= 1;
        cc ^= 1;
      }
      // 6a+6b grouped GEMM; topk 6a then 6b (dependent: 6b accumulates on 6a's output)
      float* scores2c = scores + (long)NB * SEQ * NeP;
      {
        dim3 g(NeP / 128, (2 * SEQ) / 128, NB);
        k_mfma_g2<<<g, 256, 0, stream>>>(awbE, eb, scores, SEQ, NeP, NeP,
                                         awbC, cb, scores2c, SEQ, NcP, NcP);
      }
      k_topk_update<<<NB * SEQ / 4, 256, 0, stream>>>(
          scores, SEQ, NeP, eS[ce], eV[ce], sS[cs], sV[cs], sS[cs ^ 1], sV[cs ^ 1],
          nullptr, 0, nullptr, nullptr, nullptr, nullptr, nullptr, SEQ, Ne, sc_s);
      k_topk_update<<<NB * SEQ / 4, 256, 0, stream>>>(
          scores2c, SEQ, NcP, cS[cc], cV[cc], sS[cs ^ 1], sV[cs ^ 1], sS[cs ^ 1], sV[cs ^ 1],
          nullptr, 0, nullptr, nullptr,
          ln_s_g + (long)li * DIM, ln_s_b + (long)li * DIM,
          finalLayer ? valb : nullptr, SEQ, Nc, sc_s);
      cs ^= 1;
      // 7. stabilize e/c (only when consumed) + fused next-layer step-2/3 A-panels
      if (!lastOfStage) {
        k_stab<<<cdiv((long)NB * Ne, 4), 256, 0, stream>>>(
            eS[ce], eV[ce], ln_e_g + (long)li * DIM, ln_e_b + (long)li * DIM,
            w_s2e + (long)(li + 1) * DIM, awbS2e, Ne, NeP);
        k_stab<<<cdiv((long)NB * Nc, 4), 256, 0, stream>>>(
            cS[cc], cV[cc], ln_c_g + (long)li * DIM, ln_c_b + (long)li * DIM,
            w_s2c + (long)(li + 1) * DIM, awbS2c, Nc, NcP);
      }
      ++li;
    }
  }
  // readout
  {
    dim3 g(1000, 16);
    dim3 blk(32, 8);
    k_transpose_rw<<<g, blk, 0, stream>>>(readout_w, rwT);
  }
  {
    dim3 g((NB * SEQ) / 128, 32000 / 128, 1);
    k_mfma_ro<<<g, 256, 0, stream>>>(valb, rwT, (float*)d_out, readout_b, NB * SEQ, 32000, 32000);
  }
}